// Round 14
// baseline (145.910 us; speedup 1.0000x reference)
//
#include <hip/hip_runtime.h>

// Problem constants
#define D    128      // d+1
#define DM   127      // d
#define NP1  1024     // N+1
#define B    8
#define H    8
#define NL   4
#define DD   (D*D)

typedef __attribute__((ext_vector_type(8))) __bf16 bf16x8;
typedef __attribute__((ext_vector_type(8))) unsigned short ushort8;
typedef __attribute__((ext_vector_type(4))) unsigned short ushort4v;
typedef __attribute__((ext_vector_type(4))) float f32x4;

// Workspace layout (float offsets). ~28 MB total.
#define WS_GP8  0                        // [B][8][DD]  f32 Gram partials (init, layer 0)
#define WS_GP32 (WS_GP8 + B*8*DD)        // [B][32][DD] f32 Gram partials (z, layers 1..3)
#define WS_SPT  (WS_GP32 + B*32*DD)      // [B][H][DD]  f32 Sp TRANSPOSED
#define WS_QB   (WS_SPT + B*H*DD)        // [NL][H][DD] bf16 Q*(1/N), swizzled
#define WS_PB   (WS_QB + NL*H*DD/2)      // [NL][H][DD] bf16 P padded (+corner 1), swizzled
#define WS_GB   (WS_PB + NL*H*DD/2)      // [B][DD] bf16 G, swizzled
#define WS_ST   (WS_GB + B*DD/2)         // [B][DD] bf16 S^T, swizzled

// Async global->LDS, 16B/lane (dest = wave-uniform base + lane*16; linear).
__device__ __forceinline__ void async16(const void* g, void* l)
{
    __builtin_amdgcn_global_load_lds(
        (const __attribute__((address_space(1))) void*)g,
        (__attribute__((address_space(3))) void*)l,
        16, 0, 0);
}

// fp32 -> bf16 round-to-nearest-even
__device__ __forceinline__ unsigned short f2bf(float f)
{
    unsigned int u = __float_as_uint(f);
    u += 0x7fffu + ((u >> 16) & 1u);
    return (unsigned short)(u >> 16);
}

// Swizzled elem index for bf16 [*][128] row-major tiles: col ^= (row&7)<<3.
__device__ __forceinline__ int SW(int row, int col)
{
    return row * 128 + (col ^ ((row & 7) << 3));
}

// A/B fragment from a swizzled bf16 LDS tile ([rows][128]): lane supplies
// matrix row row0+(l&15), k = k0 + (l>>4)*8 + j. k-enum cancels A vs B.
__device__ __forceinline__ bf16x8 fragAB(const unsigned short* Lb, int row0, int k0, int lane)
{
    const int r = row0 + (lane & 15);
    const int c = (k0 + ((lane >> 4) << 3)) ^ ((r & 7) << 3);
    union { ushort8 u; bf16x8 b; } U;
    U.u = *(const ushort8*)&Lb[r * 128 + c];
    return U.b;
}

// Fragment from a [128 rows][40-elem-stride] bf16 tile (K=32, unswizzled,
// pad-40 spreads banks). Same k-enumeration as fragAB -> cancels A vs B.
__device__ __forceinline__ bf16x8 frag32(const unsigned short* Lb, int row0, int lane)
{
    const int r = row0 + (lane & 15);
    const int k = (lane >> 4) << 3;
    union { ushort8 u; bf16x8 b; } U;
    U.u = *(const ushort8*)&Lb[r * 40 + k];
    return U.b;
}

#define MFMA(a, b, c) __builtin_amdgcn_mfma_f32_16x16x32_bf16((a), (b), (c), 0, 0, 0)

// ---------------------------------------------------------------------------
// init (once): blocks 0..63 = layer-0 chunk Grams of Z0 (r9/r11-proven body:
// fp32 stage + transpose-convert + [2][8] MFMA + transposed store).
// blocks 64..191 = prep (params -> bf16 swz, proven). grid 192 x 256.
// ---------------------------------------------------------------------------
__global__ __launch_bounds__(256) void init_kernel(
    const float* __restrict__ Z, float* __restrict__ Gp8,
    const float* __restrict__ ap, unsigned short* __restrict__ Qb,
    unsigned short* __restrict__ Pb)
{
    const int t = threadIdx.x;
    __shared__ __align__(16) float Zs[128 * 128];          // 64 KB
    __shared__ __align__(16) unsigned short Zt[128 * 128]; // 32 KB

    if (blockIdx.x < 64) {
        const int c = blockIdx.x & 7, b = blockIdx.x >> 3;
        const int lane = t & 63, w = t >> 6;

        const float* src = Z + ((size_t)b * NP1 + c * 128) * D;
        #pragma unroll
        for (int i = 0; i < 16; ++i)
            async16(src + (t + 256 * i) * 4, Zs + (t + 256 * i) * 4);
        __syncthreads();

        {
            const int d = t >> 1, half = t & 1;
            const int sft = (d & 7) << 3;
            #pragma unroll 4
            for (int tp = 0; tp < 32; ++tp) {
                const int tk = ((tp + d) & 31) * 2 + half * 64;
                float v0 = Zs[tk * 128 + d];
                float v1 = Zs[(tk + 1) * 128 + d];
                if (c == 7 && tk == 126) v1 = 0.f;   // key mask: token 1023
                ((unsigned int*)Zt)[(d * 128 + (tk ^ sft)) >> 1] =
                    (unsigned int)f2bf(v0) | ((unsigned int)f2bf(v1) << 16);
            }
        }
        __syncthreads();

        f32x4 acc[2][8] = {};
        #pragma unroll
        for (int k0 = 0; k0 < 128; k0 += 32) {
            const bf16x8 a0 = fragAB(Zt, (w * 2 + 0) * 16, k0, lane);
            const bf16x8 a1 = fragAB(Zt, (w * 2 + 1) * 16, k0, lane);
            #pragma unroll
            for (int nt = 0; nt < 8; ++nt) {
                const bf16x8 bb = fragAB(Zt, nt * 16, k0, lane);
                acc[0][nt] = MFMA(a0, bb, acc[0][nt]);
                acc[1][nt] = MFMA(a1, bb, acc[1][nt]);
            }
        }
        float* Gb = Gp8 + ((size_t)(b * 8 + c)) * DD;
        #pragma unroll
        for (int m = 0; m < 2; ++m) {
            const int rg = (w * 2 + m) * 16 + ((lane >> 4) << 2);
            #pragma unroll
            for (int nt = 0; nt < 8; ++nt) {
                const int cg = nt * 16 + (lane & 15);
                *(f32x4*)&Gb[cg * 128 + rg] = acc[m][nt];   // transposed (symmetric)
            }
        }
    } else {
        const int pid = blockIdx.x - 64;   // 0..127
        const float inv = 1.0f / 1023.0f;
        #pragma unroll
        for (int e = 0; e < 16; ++e) {
            const int p  = pid * 4096 + e * 256 + t;   // 0 .. 2^19-1
            const int c  = (p & 63) * 2;
            const int r  = (p >> 6) & 127;
            const int h  = (p >> 13) & 7;
            const int isP = (p >> 16) & 1;
            const int l  = (p >> 17) & 3;
            const float* apl = ap + ((size_t)(l * H + h) * 2 + (isP ? 0 : 1)) * DM * DM;
            float v0, v1;
            if (!isP) {
                v0 = (r < DM && c     < DM) ? apl[r * DM + c] * inv     : 0.f;
                v1 = (r < DM && c + 1 < DM) ? apl[r * DM + c + 1] * inv : 0.f;
            } else {
                v0 = (r < DM && c     < DM) ? apl[r * DM + c]     : 0.f;
                v1 = (r < DM && c + 1 < DM) ? apl[r * DM + c + 1]
                     : ((r == DM && c + 1 == DM) ? 1.f : 0.f);
            }
            unsigned short* base = (isP ? Pb : Qb) + (size_t)(l * H + h) * DD;
            const int el = SW(r, c);
            ((unsigned int*)base)[el >> 1] =
                (unsigned int)f2bf(v0) | ((unsigned int)f2bf(v1) << 16);
        }
    }
}

// ---------------------------------------------------------------------------
// gred: G[b] = sum of npart partials -> bf16 swizzled. grid (16, B) x 256.
// ---------------------------------------------------------------------------
__global__ __launch_bounds__(256) void gred_kernel(
    const float* __restrict__ Gp, unsigned short* __restrict__ Gbf, int npart)
{
    const int b = blockIdx.y;
    const int idx4 = blockIdx.x * 256 + threadIdx.x;   // 0..4095
    float4 sum = make_float4(0.f, 0.f, 0.f, 0.f);
    #pragma unroll 8
    for (int c = 0; c < npart; ++c) {
        const float4 v = ((const float4*)Gp)[((size_t)b * npart + c) * 4096 + idx4];
        sum.x += v.x; sum.y += v.y; sum.z += v.z; sum.w += v.w;
    }
    const int row = idx4 >> 5;
    const int n0  = (idx4 & 31) * 4;
    const int el  = SW(row, n0);
    unsigned int* dst = (unsigned int*)(Gbf + (size_t)b * DD);
    dst[(el >> 1) + 0] = (unsigned int)f2bf(sum.x) | ((unsigned int)f2bf(sum.y) << 16);
    dst[(el >> 1) + 1] = (unsigned int)f2bf(sum.z) | ((unsigned int)f2bf(sum.w) << 16);
}

// ---------------------------------------------------------------------------
// ts: T = Qf_h @ G_b; Spt = (T @ P_h^T)^T. grid (4, H, B) x 256. (proven)
// ---------------------------------------------------------------------------
__global__ __launch_bounds__(256) void ts_kernel(
    const unsigned short* __restrict__ Qb, const unsigned short* __restrict__ Pb,
    const unsigned short* __restrict__ Gbf, float* __restrict__ Spt)
{
    const int s = blockIdx.x, h = blockIdx.y, b = blockIdx.z;
    const int t = threadIdx.x, lane = t & 63, w = t >> 6;

    __shared__ __align__(16) unsigned short Qs[32 * 128];   // 8 KB
    __shared__ __align__(16) unsigned short Gs[128 * 128];  // 32 KB
    __shared__ __align__(16) unsigned short Ps[128 * 128];  // 32 KB
    __shared__ __align__(16) unsigned short Tb[32 * 128];   // 8 KB

    const unsigned short* qsrc = Qb + (size_t)h * DD + s * 32 * 128;
    #pragma unroll
    for (int i = 0; i < 2; ++i)
        async16((const char*)qsrc + (t + 256 * i) * 16, (char*)Qs + (t + 256 * i) * 16);
    const unsigned short* gsrc = Gbf + (size_t)b * DD;
    #pragma unroll
    for (int i = 0; i < 8; ++i)
        async16((const char*)gsrc + (t + 256 * i) * 16, (char*)Gs + (t + 256 * i) * 16);
    const unsigned short* psrc = Pb + (size_t)h * DD;
    #pragma unroll
    for (int i = 0; i < 8; ++i)
        async16((const char*)psrc + (t + 256 * i) * 16, (char*)Ps + (t + 256 * i) * 16);

    // wait for Q+G; Ps's 8 loads stay in flight under phase 1
    asm volatile("s_waitcnt vmcnt(8)" ::: "memory");
    __builtin_amdgcn_s_barrier();
    asm volatile("" ::: "memory");

    f32x4 accT[2][2] = {};
    #pragma unroll
    for (int k0 = 0; k0 < 128; k0 += 32) {
        const bf16x8 a0 = fragAB(Qs, 0, k0, lane);
        const bf16x8 a1 = fragAB(Qs, 16, k0, lane);
        const bf16x8 b0 = fragAB(Gs, (w * 2 + 0) * 16, k0, lane);
        const bf16x8 b1 = fragAB(Gs, (w * 2 + 1) * 16, k0, lane);
        accT[0][0] = MFMA(a0, b0, accT[0][0]);
        accT[0][1] = MFMA(a0, b1, accT[0][1]);
        accT[1][0] = MFMA(a1, b0, accT[1][0]);
        accT[1][1] = MFMA(a1, b1, accT[1][1]);
    }
    #pragma unroll
    for (int m = 0; m < 2; ++m) {
        #pragma unroll
        for (int nl = 0; nl < 2; ++nl) {
            const int cc = (w * 2 + nl) * 16 + (lane & 15);
            const int r0 = m * 16 + ((lane >> 4) << 2);
            #pragma unroll
            for (int j = 0; j < 4; ++j)
                Tb[SW(r0 + j, cc)] = f2bf(accT[m][nl][j]);
        }
    }
    __syncthreads();   // T visible; drains Ps loads

    f32x4 accS[2][2] = {};
    #pragma unroll
    for (int k0 = 0; k0 < 128; k0 += 32) {
        const bf16x8 a0 = fragAB(Tb, 0, k0, lane);
        const bf16x8 a1 = fragAB(Tb, 16, k0, lane);
        const bf16x8 b0 = fragAB(Ps, (w * 2 + 0) * 16, k0, lane);
        const bf16x8 b1 = fragAB(Ps, (w * 2 + 1) * 16, k0, lane);
        accS[0][0] = MFMA(a0, b0, accS[0][0]);
        accS[0][1] = MFMA(a0, b1, accS[0][1]);
        accS[1][0] = MFMA(a1, b0, accS[1][0]);
        accS[1][1] = MFMA(a1, b1, accS[1][1]);
    }

    float* SptBH = Spt + (size_t)(b * 8 + h) * DD;
    #pragma unroll
    for (int m = 0; m < 2; ++m) {
        const int rg = s * 32 + m * 16 + ((lane >> 4) << 2);
        #pragma unroll
        for (int nl = 0; nl < 2; ++nl) {
            const int cg = (w * 2 + nl) * 16 + (lane & 15);
            *(f32x4*)&SptBH[cg * 128 + rg] = accS[m][nl];
        }
    }
}

// ---------------------------------------------------------------------------
// sred: St = bf16( sum_h Spt[b][h] ), swizzled. grid (16, B) x 256. (proven)
// ---------------------------------------------------------------------------
__global__ __launch_bounds__(256) void sred_kernel(
    const float* __restrict__ Spt, unsigned short* __restrict__ St)
{
    const int b = blockIdx.y;
    const int idx4 = blockIdx.x * 256 + threadIdx.x;
    float4 sum = make_float4(0.f, 0.f, 0.f, 0.f);
    #pragma unroll
    for (int h = 0; h < 8; ++h) {
        const float4 v = ((const float4*)Spt)[(size_t)(b * 8 + h) * 4096 + idx4];
        sum.x += v.x; sum.y += v.y; sum.z += v.z; sum.w += v.w;
    }
    const int row = idx4 >> 5;
    const int k0  = (idx4 & 31) * 4;
    const int el  = SW(row, k0);
    unsigned int* dst = (unsigned int*)(St + (size_t)b * DD);
    dst[(el >> 1) + 0] = (unsigned int)f2bf(sum.x) | ((unsigned int)f2bf(sum.y) << 16);
    dst[(el >> 1) + 1] = (unsigned int)f2bf(sum.z) | ((unsigned int)f2bf(sum.w) << 16);
}

// ---------------------------------------------------------------------------
// z: out = Z + Z @ S via MFMA (r10/r13-proven core). If writeG: also emit
// this block's 32-token Gram partial of the OUTPUT into Gp32[b][sblk]
// (transpose-convert output rows -> [128][40] bf16 tile, K=32 MFMA,
// transposed f32 store — each chunk Gram is symmetric). grid (32, B) x 256.
// LDS = 16 + 8 + 32 + 10 = 66 KB.
// ---------------------------------------------------------------------------
__global__ __launch_bounds__(256) void z_kernel(
    const float* __restrict__ Zin, const unsigned short* __restrict__ St,
    float* __restrict__ Zout, float* __restrict__ Gp32, int writeG)
{
    const int sblk = blockIdx.x, b = blockIdx.y;
    const int t = threadIdx.x, lane = t & 63, w = t >> 6;

    __shared__ __align__(16) float Zs[32 * 128];            // 16 KB fp32 rows (in, then out)
    __shared__ __align__(16) unsigned short Zb[32 * 128];   // 8 KB bf16 swizzled
    __shared__ __align__(16) unsigned short Ss[DD];         // 32 KB bf16 swizzled (S^T)
    __shared__ __align__(16) unsigned short Zt32[128 * 40]; // 10 KB [dim][tok] pad-40

    const float* zsrc = Zin + ((size_t)b * NP1 + sblk * 32) * D;
    #pragma unroll
    for (int i = 0; i < 4; ++i)
        async16(zsrc + (t + 256 * i) * 4, Zs + (t + 256 * i) * 4);
    const unsigned short* ssrc = St + (size_t)b * DD;
    #pragma unroll
    for (int i = 0; i < 8; ++i)
        async16((const char*)ssrc + (t + 256 * i) * 16, (char*)Ss + (t + 256 * i) * 16);

    asm volatile("s_waitcnt vmcnt(8)" ::: "memory");
    __builtin_amdgcn_s_barrier();
    asm volatile("" ::: "memory");

    {
        const int r = t >> 3, c0 = (t & 7) * 16;
        const int sft = (r & 7) << 3;
        #pragma unroll
        for (int cc = 0; cc < 16; cc += 2) {
            const float v0 = Zs[r * 128 + c0 + cc];
            const float v1 = Zs[r * 128 + c0 + cc + 1];
            ((unsigned int*)Zb)[(r * 128 + ((c0 + cc) ^ sft)) >> 1] =
                (unsigned int)f2bf(v0) | ((unsigned int)f2bf(v1) << 16);
        }
    }
    __syncthreads();   // Zb visible; drains Ss loads

    f32x4 accR[2][2] = {};
    #pragma unroll
    for (int k0 = 0; k0 < 128; k0 += 32) {
        const bf16x8 a0 = fragAB(Zb, 0, k0, lane);
        const bf16x8 a1 = fragAB(Zb, 16, k0, lane);
        const bf16x8 b0 = fragAB(Ss, (w * 2 + 0) * 16, k0, lane);
        const bf16x8 b1 = fragAB(Ss, (w * 2 + 1) * 16, k0, lane);
        accR[0][0] = MFMA(a0, b0, accR[0][0]);
        accR[0][1] = MFMA(a0, b1, accR[0][1]);
        accR[1][0] = MFMA(a1, b0, accR[1][0]);
        accR[1][1] = MFMA(a1, b1, accR[1][1]);
    }

    // epilogue: out = Zs + res; write out rows back into Zs (each element
    // owned by exactly one thread -> no race)
    #pragma unroll
    for (int m = 0; m < 2; ++m) {
        const int r0 = m * 16 + ((lane >> 4) << 2);
        #pragma unroll
        for (int nl = 0; nl < 2; ++nl) {
            const int cc = (w * 2 + nl) * 16 + (lane & 15);
            #pragma unroll
            for (int j = 0; j < 4; ++j) {
                const int r = r0 + j;
                const float o = Zs[r * 128 + cc] + accR[m][nl][j];
                Zout[((size_t)b * NP1 + sblk * 32 + r) * D + cc] = o;
                Zs[r * 128 + cc] = o;
            }
        }
    }

    if (writeG) {
        __syncthreads();   // all output rows in Zs
        // transpose-convert: Zt32[d][tok] = bf16(out[tok][d]); mask token 1023
        {
            const int dd = t >> 1, half = t & 1;
            #pragma unroll
            for (int i = 0; i < 16; i += 2) {
                const int tok = half * 16 + i;
                float v0 = Zs[tok * 128 + dd];
                float v1 = Zs[(tok + 1) * 128 + dd];
                if (sblk == 31 && tok + 1 == 31) v1 = 0.f;   // token 1023
                ((unsigned int*)Zt32)[(dd * 40 + tok) >> 1] =
                    (unsigned int)f2bf(v0) | ((unsigned int)f2bf(v1) << 16);
            }
        }
        __syncthreads();

        // Gram partial over this block's 32 tokens: one K=32 MFMA step per tile
        f32x4 gpa[2][8] = {};
        const bf16x8 a0 = frag32(Zt32, (w * 2 + 0) * 16, lane);
        const bf16x8 a1 = frag32(Zt32, (w * 2 + 1) * 16, lane);
        #pragma unroll
        for (int nt = 0; nt < 8; ++nt) {
            const bf16x8 bb = frag32(Zt32, nt * 16, lane);
            gpa[0][nt] = MFMA(a0, bb, gpa[0][nt]);
            gpa[1][nt] = MFMA(a1, bb, gpa[1][nt]);
        }
        float* Gb = Gp32 + ((size_t)(b * 32 + sblk)) * DD;
        #pragma unroll
        for (int m = 0; m < 2; ++m) {
            const int rg = (w * 2 + m) * 16 + ((lane >> 4) << 2);
            #pragma unroll
            for (int nt = 0; nt < 8; ++nt) {
                const int cg = nt * 16 + (lane & 15);
                *(f32x4*)&Gb[cg * 128 + rg] = gpa[m][nt];   // transposed (symmetric)
            }
        }
    }
}

// ---------------------------------------------------------------------------
extern "C" void kernel_launch(void* const* d_in, const int* in_sizes, int n_in,
                              void* d_out, int out_size, void* d_ws, size_t ws_size,
                              hipStream_t stream)
{
    const float* Z0 = (const float*)d_in[0];
    const float* ap = (const float*)d_in[1];
    float* out = (float*)d_out;
    float* ws  = (float*)d_ws;

    float* Gp8  = ws + WS_GP8;
    float* Gp32 = ws + WS_GP32;
    float* Spt  = ws + WS_SPT;
    unsigned short* Qb  = (unsigned short*)(ws + WS_QB);
    unsigned short* Pb  = (unsigned short*)(ws + WS_PB);
    unsigned short* Gbf = (unsigned short*)(ws + WS_GB);
    unsigned short* St  = (unsigned short*)(ws + WS_ST);

    hipLaunchKernelGGL(init_kernel, dim3(192), dim3(256), 0, stream, Z0, Gp8, ap, Qb, Pb);

    const float* Zcur = Z0;
    for (int l = 0; l < NL; ++l) {
        const unsigned short* Qbl = Qb + (size_t)l * H * DD;
        const unsigned short* Pbl = Pb + (size_t)l * H * DD;
        if (l == 0)
            hipLaunchKernelGGL(gred_kernel, dim3(16, B), dim3(256), 0, stream, Gp8, Gbf, 8);
        else
            hipLaunchKernelGGL(gred_kernel, dim3(16, B), dim3(256), 0, stream, Gp32, Gbf, 32);
        hipLaunchKernelGGL(ts_kernel,   dim3(4, H, B), dim3(256), 0, stream, Qbl, Pbl, Gbf, Spt);
        hipLaunchKernelGGL(sred_kernel, dim3(16, B),   dim3(256), 0, stream, Spt, St);
        hipLaunchKernelGGL(z_kernel,    dim3(32, B),   dim3(256), 0, stream,
                           Zcur, St, out, Gp32, (l < NL - 1) ? 1 : 0);
        Zcur = out;
    }
}

// Round 15
// 136.930 us; speedup vs baseline: 1.0656x; 1.0656x over previous
//
#include <hip/hip_runtime.h>

// Problem constants
#define D    128      // d+1
#define DM   127      // d
#define NP1  1024     // N+1
#define B    8
#define H    8
#define NL   4
#define DD   (D*D)

typedef __attribute__((ext_vector_type(8))) __bf16 bf16x8;
typedef __attribute__((ext_vector_type(8))) unsigned short ushort8;
typedef __attribute__((ext_vector_type(4))) unsigned short ushort4v;
typedef __attribute__((ext_vector_type(4))) float f32x4;

// Workspace layout (float offsets). ~10.5 MB total.
#define WS_GP  0                        // [B][8][DD] f32 Gram partials (symmetric)
#define WS_SPT (WS_GP + B*8*DD)         // [B][H][DD] bf16 Sp^T partials, swizzled (final layout)
#define WS_QB  (WS_SPT + B*H*DD/2)      // [NL][H][DD] bf16 Q*(1/N), swizzled
#define WS_PB  (WS_QB + NL*H*DD/2)      // [NL][H][DD] bf16 P padded (+corner 1), swizzled
#define WS_GB  (WS_PB + NL*H*DD/2)      // [B][DD] bf16 G, swizzled
#define WS_ST  (WS_GB + B*DD/2)         // [B][DD] bf16 S^T, swizzled
#define WS_ZT  (WS_ST + B*DD/2)         // [B][8][DD] bf16 Z^T per chunk, swizzled, tok1023-masked

// Async global->LDS, 16B/lane (dest = wave-uniform base + lane*16; linear).
__device__ __forceinline__ void async16(const void* g, void* l)
{
    __builtin_amdgcn_global_load_lds(
        (const __attribute__((address_space(1))) void*)g,
        (__attribute__((address_space(3))) void*)l,
        16, 0, 0);
}

// fp32 -> bf16 round-to-nearest-even
__device__ __forceinline__ unsigned short f2bf(float f)
{
    unsigned int u = __float_as_uint(f);
    u += 0x7fffu + ((u >> 16) & 1u);
    return (unsigned short)(u >> 16);
}
__device__ __forceinline__ float bf2f(unsigned short v)
{
    return __uint_as_float((unsigned int)v << 16);
}

// Swizzled elem index for bf16 [*][128] row-major tiles: col ^= (row&7)<<3.
__device__ __forceinline__ int SW(int row, int col)
{
    return row * 128 + (col ^ ((row & 7) << 3));
}

// A/B fragment from a swizzled bf16 LDS tile: lane supplies matrix row
// row0+(l&15), k = k0 + (l>>4)*8 + j. k-enumeration cancels between A and B.
__device__ __forceinline__ bf16x8 fragAB(const unsigned short* Lb, int row0, int k0, int lane)
{
    const int r = row0 + (lane & 15);
    const int c = (k0 + ((lane >> 4) << 3)) ^ ((r & 7) << 3);
    union { ushort8 u; bf16x8 b; } U;
    U.u = *(const ushort8*)&Lb[r * 128 + c];
    return U.b;
}
__device__ __forceinline__ ushort4v packbf(f32x4 a)
{
    ushort4v v;
    v[0] = f2bf(a[0]); v[1] = f2bf(a[1]); v[2] = f2bf(a[2]); v[3] = f2bf(a[3]);
    return v;
}

#define MFMA(a, b, c) __builtin_amdgcn_mfma_f32_16x16x32_bf16((a), (b), (c), 0, 0, 0)

// ---------------------------------------------------------------------------
// init (once, merged prologue): blocks 0..63 = ztr0 (Ztr from Z0, r10-proven);
// blocks 64..191 = prep (params -> bf16 swz, r9-proven). grid 192 x 256.
// ---------------------------------------------------------------------------
__global__ __launch_bounds__(256) void init_kernel(
    const float* __restrict__ Z, unsigned short* __restrict__ Ztr,
    const float* __restrict__ ap, unsigned short* __restrict__ Qb,
    unsigned short* __restrict__ Pb)
{
    const int t = threadIdx.x;
    __shared__ __align__(16) float Zs[128 * 128];          // 64 KB
    __shared__ __align__(16) unsigned short Zt[128 * 128]; // 32 KB

    if (blockIdx.x < 64) {
        const int c = blockIdx.x & 7, b = blockIdx.x >> 3;

        const float* src = Z + ((size_t)b * NP1 + c * 128) * D;
        #pragma unroll
        for (int i = 0; i < 16; ++i)
            async16(src + (t + 256 * i) * 4, Zs + (t + 256 * i) * 4);
        __syncthreads();

        {
            const int d = t >> 1, half = t & 1;
            const int sft = (d & 7) << 3;
            #pragma unroll 4
            for (int tp = 0; tp < 32; ++tp) {
                const int tk = ((tp + d) & 31) * 2 + half * 64;
                float v0 = Zs[tk * 128 + d];
                float v1 = Zs[(tk + 1) * 128 + d];
                if (c == 7 && tk == 126) v1 = 0.f;   // key mask: token 1023
                ((unsigned int*)Zt)[(d * 128 + (tk ^ sft)) >> 1] =
                    (unsigned int)f2bf(v0) | ((unsigned int)f2bf(v1) << 16);
            }
        }
        __syncthreads();

        ushort8* dst = (ushort8*)(Ztr + (size_t)(b * 8 + c) * DD);
        #pragma unroll
        for (int i = 0; i < 8; ++i)
            dst[t + 256 * i] = ((const ushort8*)Zt)[t + 256 * i];
    } else {
        const int pid = blockIdx.x - 64;   // 0..127
        const float inv = 1.0f / 1023.0f;
        #pragma unroll
        for (int e = 0; e < 16; ++e) {
            const int p  = pid * 4096 + e * 256 + t;   // 0 .. 2^19-1
            const int c  = (p & 63) * 2;
            const int r  = (p >> 6) & 127;
            const int h  = (p >> 13) & 7;
            const int isP = (p >> 16) & 1;
            const int l  = (p >> 17) & 3;
            const float* apl = ap + ((size_t)(l * H + h) * 2 + (isP ? 0 : 1)) * DM * DM;
            float v0, v1;
            if (!isP) {
                v0 = (r < DM && c     < DM) ? apl[r * DM + c] * inv     : 0.f;
                v1 = (r < DM && c + 1 < DM) ? apl[r * DM + c + 1] * inv : 0.f;
            } else {
                v0 = (r < DM && c     < DM) ? apl[r * DM + c]     : 0.f;
                v1 = (r < DM && c + 1 < DM) ? apl[r * DM + c + 1]
                     : ((r == DM && c + 1 == DM) ? 1.f : 0.f);
            }
            unsigned short* base = (isP ? Pb : Qb) + (size_t)(l * H + h) * DD;
            const int el = SW(r, c);
            ((unsigned int*)base)[el >> 1] =
                (unsigned int)f2bf(v0) | ((unsigned int)f2bf(v1) << 16);
        }
    }
}

// ---------------------------------------------------------------------------
// gp: Gram partial of chunk c via MFMA, directly from bf16 Ztr.
// grid (8 chunks, 4 n-quarters, B) = 256 blocks x 256. LDS = 32 KB. (r10-proven)
// ---------------------------------------------------------------------------
__global__ __launch_bounds__(256) void gp_kernel(
    const unsigned short* __restrict__ Ztr, float* __restrict__ Gp)
{
    const int c = blockIdx.x, q = blockIdx.y, b = blockIdx.z;
    const int t = threadIdx.x, lane = t & 63, w = t >> 6;

    __shared__ __align__(16) unsigned short Zt[128 * 128]; // 32 KB

    const unsigned short* src = Ztr + (size_t)(b * 8 + c) * DD;
    #pragma unroll
    for (int i = 0; i < 8; ++i)
        async16((const char*)src + (t + 256 * i) * 16, (char*)Zt + (t + 256 * i) * 16);
    __syncthreads();

    f32x4 acc[2][2] = {};
    #pragma unroll
    for (int k0 = 0; k0 < 128; k0 += 32) {
        const bf16x8 a0 = fragAB(Zt, (w * 2 + 0) * 16, k0, lane);
        const bf16x8 a1 = fragAB(Zt, (w * 2 + 1) * 16, k0, lane);
        const bf16x8 b0 = fragAB(Zt, q * 32,      k0, lane);
        const bf16x8 b1 = fragAB(Zt, q * 32 + 16, k0, lane);
        acc[0][0] = MFMA(a0, b0, acc[0][0]);
        acc[0][1] = MFMA(a0, b1, acc[0][1]);
        acc[1][0] = MFMA(a1, b0, acc[1][0]);
        acc[1][1] = MFMA(a1, b1, acc[1][1]);
    }

    float* Gb = Gp + ((size_t)(b * 8 + c)) * DD;
    #pragma unroll
    for (int m = 0; m < 2; ++m) {
        const int rg = (w * 2 + m) * 16 + ((lane >> 4) << 2);
        #pragma unroll
        for (int nl = 0; nl < 2; ++nl) {
            const int cg = q * 32 + nl * 16 + (lane & 15);
            *(f32x4*)&Gb[cg * 128 + rg] = acc[m][nl];   // transposed store (symmetric)
        }
    }
}

// ---------------------------------------------------------------------------
// gred: G[b] = sum_c Gp[b][c] -> bf16 swizzled. grid (16, B) x 256. (proven)
// ---------------------------------------------------------------------------
__global__ __launch_bounds__(256) void gred_kernel(
    const float* __restrict__ Gp, unsigned short* __restrict__ Gbf)
{
    const int b = blockIdx.y;
    const int idx4 = blockIdx.x * 256 + threadIdx.x;   // 0..4095
    float4 sum = make_float4(0.f, 0.f, 0.f, 0.f);
    #pragma unroll
    for (int c = 0; c < 8; ++c) {
        const float4 v = ((const float4*)Gp)[(size_t)(b * 8 + c) * 4096 + idx4];
        sum.x += v.x; sum.y += v.y; sum.z += v.z; sum.w += v.w;
    }
    const int row = idx4 >> 5;
    const int n0  = (idx4 & 31) * 4;
    const int el  = SW(row, n0);
    unsigned int* dst = (unsigned int*)(Gbf + (size_t)b * DD);
    dst[(el >> 1) + 0] = (unsigned int)f2bf(sum.x) | ((unsigned int)f2bf(sum.y) << 16);
    dst[(el >> 1) + 1] = (unsigned int)f2bf(sum.z) | ((unsigned int)f2bf(sum.w) << 16);
}

// ---------------------------------------------------------------------------
// ts: T = Qf_h @ G_b; Spt = (T @ P_h^T)^T stored bf16 in the FINAL swizzled
// S^T layout (r11-proven store). grid (4, H, B) x 256.
// ---------------------------------------------------------------------------
__global__ __launch_bounds__(256) void ts_kernel(
    const unsigned short* __restrict__ Qb, const unsigned short* __restrict__ Pb,
    const unsigned short* __restrict__ Gbf, unsigned short* __restrict__ Spt)
{
    const int s = blockIdx.x, h = blockIdx.y, b = blockIdx.z;
    const int t = threadIdx.x, lane = t & 63, w = t >> 6;

    __shared__ __align__(16) unsigned short Qs[32 * 128];   // 8 KB
    __shared__ __align__(16) unsigned short Gs[128 * 128];  // 32 KB
    __shared__ __align__(16) unsigned short Ps[128 * 128];  // 32 KB
    __shared__ __align__(16) unsigned short Tb[32 * 128];   // 8 KB

    const unsigned short* qsrc = Qb + (size_t)h * DD + s * 32 * 128;
    #pragma unroll
    for (int i = 0; i < 2; ++i)
        async16((const char*)qsrc + (t + 256 * i) * 16, (char*)Qs + (t + 256 * i) * 16);
    const unsigned short* gsrc = Gbf + (size_t)b * DD;
    #pragma unroll
    for (int i = 0; i < 8; ++i)
        async16((const char*)gsrc + (t + 256 * i) * 16, (char*)Gs + (t + 256 * i) * 16);
    const unsigned short* psrc = Pb + (size_t)h * DD;
    #pragma unroll
    for (int i = 0; i < 8; ++i)
        async16((const char*)psrc + (t + 256 * i) * 16, (char*)Ps + (t + 256 * i) * 16);

    // wait for Q+G; Ps's 8 loads stay in flight under phase 1
    asm volatile("s_waitcnt vmcnt(8)" ::: "memory");
    __builtin_amdgcn_s_barrier();
    asm volatile("" ::: "memory");

    f32x4 accT[2][2] = {};
    #pragma unroll
    for (int k0 = 0; k0 < 128; k0 += 32) {
        const bf16x8 a0 = fragAB(Qs, 0, k0, lane);
        const bf16x8 a1 = fragAB(Qs, 16, k0, lane);
        const bf16x8 b0 = fragAB(Gs, (w * 2 + 0) * 16, k0, lane);
        const bf16x8 b1 = fragAB(Gs, (w * 2 + 1) * 16, k0, lane);
        accT[0][0] = MFMA(a0, b0, accT[0][0]);
        accT[0][1] = MFMA(a0, b1, accT[0][1]);
        accT[1][0] = MFMA(a1, b0, accT[1][0]);
        accT[1][1] = MFMA(a1, b1, accT[1][1]);
    }
    #pragma unroll
    for (int m = 0; m < 2; ++m) {
        #pragma unroll
        for (int nl = 0; nl < 2; ++nl) {
            const int cc = (w * 2 + nl) * 16 + (lane & 15);
            const int r0 = m * 16 + ((lane >> 4) << 2);
            #pragma unroll
            for (int j = 0; j < 4; ++j)
                Tb[SW(r0 + j, cc)] = f2bf(accT[m][nl][j]);
        }
    }
    __syncthreads();   // T visible; drains Ps loads

    f32x4 accS[2][2] = {};
    #pragma unroll
    for (int k0 = 0; k0 < 128; k0 += 32) {
        const bf16x8 a0 = fragAB(Tb, 0, k0, lane);
        const bf16x8 a1 = fragAB(Tb, 16, k0, lane);
        const bf16x8 b0 = fragAB(Ps, (w * 2 + 0) * 16, k0, lane);
        const bf16x8 b1 = fragAB(Ps, (w * 2 + 1) * 16, k0, lane);
        accS[0][0] = MFMA(a0, b0, accS[0][0]);
        accS[0][1] = MFMA(a0, b1, accS[0][1]);
        accS[1][0] = MFMA(a1, b0, accS[1][0]);
        accS[1][1] = MFMA(a1, b1, accS[1][1]);
    }

    // bf16 transposed-packed store in the FINAL S^T swizzled layout
    unsigned short* dst = Spt + (size_t)(b * 8 + h) * DD;
    #pragma unroll
    for (int m = 0; m < 2; ++m) {
        const int rg0 = s * 32 + m * 16 + ((lane >> 4) << 2);
        #pragma unroll
        for (int nl = 0; nl < 2; ++nl) {
            const int cg = (w * 2 + nl) * 16 + (lane & 15);
            *(ushort4v*)&dst[SW(cg, rg0)] = packbf(accS[m][nl]);
        }
    }
}

// ---------------------------------------------------------------------------
// sred: St = bf16( sum_h Spt[b][h] ) — partials already in final layout, so
// a pure element-wise ushort8 stream-sum. grid (8, B) x 256.
// ---------------------------------------------------------------------------
__global__ __launch_bounds__(256) void sred_kernel(
    const unsigned short* __restrict__ Spt, unsigned short* __restrict__ St)
{
    const int b = blockIdx.y;
    const int ch = blockIdx.x * 256 + threadIdx.x;   // 0..2047 ushort8 chunks
    const unsigned short* sp0 = Spt + (size_t)b * 8 * DD;
    float a[8] = {0.f, 0.f, 0.f, 0.f, 0.f, 0.f, 0.f, 0.f};
    #pragma unroll
    for (int h = 0; h < 8; ++h) {
        const ushort8 uu = *(const ushort8*)&sp0[(size_t)h * DD + ch * 8];
        #pragma unroll
        for (int e = 0; e < 8; ++e) a[e] += bf2f(uu[e]);
    }
    ushort8 o;
    #pragma unroll
    for (int e = 0; e < 8; ++e) o[e] = f2bf(a[e]);
    *(ushort8*)&St[(size_t)b * DD + ch * 8] = o;
}

// ---------------------------------------------------------------------------
// z: out = Z + Z @ S via MFMA; also emits next layer's Ztr (bf16 transposed
// swizzled, token-1023-masked) straight from the epilogue registers.
// grid (32, B) x 256. LDS = 56 KB. (r10/r13-proven)
// ---------------------------------------------------------------------------
__global__ __launch_bounds__(256) void z_kernel(
    const float* __restrict__ Zin, const unsigned short* __restrict__ St,
    float* __restrict__ Zout, unsigned short* __restrict__ Ztr, int writeZtr)
{
    const int sblk = blockIdx.x, b = blockIdx.y;
    const int t = threadIdx.x, lane = t & 63, w = t >> 6;

    __shared__ __align__(16) float Zs[32 * 128];            // 16 KB fp32 staging
    __shared__ __align__(16) unsigned short Zb[32 * 128];   // 8 KB bf16 swizzled
    __shared__ __align__(16) unsigned short Ss[128 * 128];  // 32 KB bf16 swizzled (S^T)

    const float* zsrc = Zin + ((size_t)b * NP1 + sblk * 32) * D;
    #pragma unroll
    for (int i = 0; i < 4; ++i)
        async16(zsrc + (t + 256 * i) * 4, Zs + (t + 256 * i) * 4);
    const unsigned short* ssrc = St + (size_t)b * DD;
    #pragma unroll
    for (int i = 0; i < 8; ++i)
        async16((const char*)ssrc + (t + 256 * i) * 16, (char*)Ss + (t + 256 * i) * 16);

    asm volatile("s_waitcnt vmcnt(8)" ::: "memory");
    __builtin_amdgcn_s_barrier();
    asm volatile("" ::: "memory");

    {
        const int r = t >> 3, c0 = (t & 7) * 16;
        const int sft = (r & 7) << 3;
        #pragma unroll
        for (int cc = 0; cc < 16; cc += 2) {
            const float v0 = Zs[r * 128 + c0 + cc];
            const float v1 = Zs[r * 128 + c0 + cc + 1];
            ((unsigned int*)Zb)[(r * 128 + ((c0 + cc) ^ sft)) >> 1] =
                (unsigned int)f2bf(v0) | ((unsigned int)f2bf(v1) << 16);
        }
    }
    __syncthreads();   // Zb visible; drains Ss loads

    f32x4 accR[2][2] = {};
    #pragma unroll
    for (int k0 = 0; k0 < 128; k0 += 32) {
        const bf16x8 a0 = fragAB(Zb, 0, k0, lane);
        const bf16x8 a1 = fragAB(Zb, 16, k0, lane);
        const bf16x8 b0 = fragAB(Ss, (w * 2 + 0) * 16, k0, lane);
        const bf16x8 b1 = fragAB(Ss, (w * 2 + 1) * 16, k0, lane);
        accR[0][0] = MFMA(a0, b0, accR[0][0]);
        accR[0][1] = MFMA(a0, b1, accR[0][1]);
        accR[1][0] = MFMA(a1, b0, accR[1][0]);
        accR[1][1] = MFMA(a1, b1, accR[1][1]);
    }

    // epilogue: out = Zs + res; optional transposed bf16 emit for next gp
    #pragma unroll
    for (int m = 0; m < 2; ++m) {
        const int r0 = m * 16 + ((lane >> 4) << 2);
        #pragma unroll
        for (int nl = 0; nl < 2; ++nl) {
            const int cc = (w * 2 + nl) * 16 + (lane & 15);
            float o[4];
            #pragma unroll
            for (int j = 0; j < 4; ++j) {
                const int r = r0 + j;
                o[j] = Zs[r * 128 + cc] + accR[m][nl][j];
                Zout[((size_t)b * NP1 + sblk * 32 + r) * D + cc] = o[j];
            }
            if (writeZtr) {
                const int gt0   = sblk * 32 + r0;       // global token of j=0
                const int chunk = gt0 >> 7;
                const int tok0  = gt0 & 127;            // 4-aligned -> 8B run contiguous under SW
                ushort4v v;
                #pragma unroll
                for (int j = 0; j < 4; ++j)
                    v[j] = (gt0 + j == 1023) ? (unsigned short)0 : f2bf(o[j]);
                unsigned short* tile = Ztr + (size_t)(b * 8 + chunk) * DD;
                *(ushort4v*)&tile[SW(cc, tok0)] = v;
            }
        }
    }
}

// ---------------------------------------------------------------------------
extern "C" void kernel_launch(void* const* d_in, const int* in_sizes, int n_in,
                              void* d_out, int out_size, void* d_ws, size_t ws_size,
                              hipStream_t stream)
{
    const float* Z0 = (const float*)d_in[0];
    const float* ap = (const float*)d_in[1];
    float* out = (float*)d_out;
    float* ws  = (float*)d_ws;

    float* Gp = ws + WS_GP;
    unsigned short* Spt = (unsigned short*)(ws + WS_SPT);
    unsigned short* Qb  = (unsigned short*)(ws + WS_QB);
    unsigned short* Pb  = (unsigned short*)(ws + WS_PB);
    unsigned short* Gbf = (unsigned short*)(ws + WS_GB);
    unsigned short* St  = (unsigned short*)(ws + WS_ST);
    unsigned short* Ztr = (unsigned short*)(ws + WS_ZT);

    hipLaunchKernelGGL(init_kernel, dim3(192), dim3(256), 0, stream, Z0, Ztr, ap, Qb, Pb);

    const float* Zcur = Z0;
    for (int l = 0; l < NL; ++l) {
        const unsigned short* Qbl = Qb + (size_t)l * H * DD;
        const unsigned short* Pbl = Pb + (size_t)l * H * DD;
        hipLaunchKernelGGL(gp_kernel,   dim3(8, 4, B), dim3(256), 0, stream, Ztr, Gp);
        hipLaunchKernelGGL(gred_kernel, dim3(16, B),   dim3(256), 0, stream, Gp, Gbf);
        hipLaunchKernelGGL(ts_kernel,   dim3(4, H, B), dim3(256), 0, stream, Qbl, Pbl, Gbf, Spt);
        hipLaunchKernelGGL(sred_kernel, dim3(8, B),    dim3(256), 0, stream, Spt, St);
        hipLaunchKernelGGL(z_kernel,    dim3(32, B),   dim3(256), 0, stream,
                           Zcur, St, out, Ztr, (l < NL - 1) ? 1 : 0);
        Zcur = out;
    }
}

// Round 16
// 132.215 us; speedup vs baseline: 1.1036x; 1.0357x over previous
//
#include <hip/hip_runtime.h>

// Problem constants
#define D    128      // d+1
#define DM   127      // d
#define NP1  1024     // N+1
#define B    8
#define H    8
#define NL   4
#define DD   (D*D)

typedef __attribute__((ext_vector_type(8))) __bf16 bf16x8;
typedef __attribute__((ext_vector_type(8))) unsigned short ushort8;
typedef __attribute__((ext_vector_type(4))) unsigned short ushort4v;
typedef __attribute__((ext_vector_type(4))) float f32x4;

// Workspace layout (float offsets). ~8.5 MB total.
#define WS_GP  0                        // [B][8][DD] bf16 Gram partials, swizzled (final layout)
#define WS_SPT (WS_GP + B*8*DD/2)       // [B][H][DD] bf16 Sp^T partials, swizzled (final layout)
#define WS_QB  (WS_SPT + B*H*DD/2)      // [NL][H][DD] bf16 Q*(1/N), swizzled
#define WS_PB  (WS_QB + NL*H*DD/2)      // [NL][H][DD] bf16 P padded (+corner 1), swizzled
#define WS_GB  (WS_PB + NL*H*DD/2)      // [B][DD] bf16 G, swizzled
#define WS_ST  (WS_GB + B*DD/2)         // [B][DD] bf16 S^T, swizzled
#define WS_ZT  (WS_ST + B*DD/2)         // [B][8][DD] bf16 Z^T per chunk, swizzled, tok1023-masked

// Async global->LDS, 16B/lane (dest = wave-uniform base + lane*16; linear).
__device__ __forceinline__ void async16(const void* g, void* l)
{
    __builtin_amdgcn_global_load_lds(
        (const __attribute__((address_space(1))) void*)g,
        (__attribute__((address_space(3))) void*)l,
        16, 0, 0);
}

// fp32 -> bf16 round-to-nearest-even
__device__ __forceinline__ unsigned short f2bf(float f)
{
    unsigned int u = __float_as_uint(f);
    u += 0x7fffu + ((u >> 16) & 1u);
    return (unsigned short)(u >> 16);
}
__device__ __forceinline__ float bf2f(unsigned short v)
{
    return __uint_as_float((unsigned int)v << 16);
}

// Swizzled elem index for bf16 [*][128] row-major tiles: col ^= (row&7)<<3.
__device__ __forceinline__ int SW(int row, int col)
{
    return row * 128 + (col ^ ((row & 7) << 3));
}

// A/B fragment from a swizzled bf16 LDS tile: lane supplies matrix row
// row0+(l&15), k = k0 + (l>>4)*8 + j. k-enumeration cancels between A and B.
__device__ __forceinline__ bf16x8 fragAB(const unsigned short* Lb, int row0, int k0, int lane)
{
    const int r = row0 + (lane & 15);
    const int c = (k0 + ((lane >> 4) << 3)) ^ ((r & 7) << 3);
    union { ushort8 u; bf16x8 b; } U;
    U.u = *(const ushort8*)&Lb[r * 128 + c];
    return U.b;
}
__device__ __forceinline__ ushort4v packbf(f32x4 a)
{
    ushort4v v;
    v[0] = f2bf(a[0]); v[1] = f2bf(a[1]); v[2] = f2bf(a[2]); v[3] = f2bf(a[3]);
    return v;
}

#define MFMA(a, b, c) __builtin_amdgcn_mfma_f32_16x16x32_bf16((a), (b), (c), 0, 0, 0)

// ---------------------------------------------------------------------------
// init (once, merged prologue): blocks 0..63 = ztr0 (Ztr from Z0, r10-proven);
// blocks 64..191 = prep (params -> bf16 swz, r9-proven). grid 192 x 256.
// ---------------------------------------------------------------------------
__global__ __launch_bounds__(256) void init_kernel(
    const float* __restrict__ Z, unsigned short* __restrict__ Ztr,
    const float* __restrict__ ap, unsigned short* __restrict__ Qb,
    unsigned short* __restrict__ Pb)
{
    const int t = threadIdx.x;
    __shared__ __align__(16) float Zs[128 * 128];          // 64 KB
    __shared__ __align__(16) unsigned short Zt[128 * 128]; // 32 KB

    if (blockIdx.x < 64) {
        const int c = blockIdx.x & 7, b = blockIdx.x >> 3;

        const float* src = Z + ((size_t)b * NP1 + c * 128) * D;
        #pragma unroll
        for (int i = 0; i < 16; ++i)
            async16(src + (t + 256 * i) * 4, Zs + (t + 256 * i) * 4);
        __syncthreads();

        {
            const int d = t >> 1, half = t & 1;
            const int sft = (d & 7) << 3;
            #pragma unroll 4
            for (int tp = 0; tp < 32; ++tp) {
                const int tk = ((tp + d) & 31) * 2 + half * 64;
                float v0 = Zs[tk * 128 + d];
                float v1 = Zs[(tk + 1) * 128 + d];
                if (c == 7 && tk == 126) v1 = 0.f;   // key mask: token 1023
                ((unsigned int*)Zt)[(d * 128 + (tk ^ sft)) >> 1] =
                    (unsigned int)f2bf(v0) | ((unsigned int)f2bf(v1) << 16);
            }
        }
        __syncthreads();

        ushort8* dst = (ushort8*)(Ztr + (size_t)(b * 8 + c) * DD);
        #pragma unroll
        for (int i = 0; i < 8; ++i)
            dst[t + 256 * i] = ((const ushort8*)Zt)[t + 256 * i];
    } else {
        const int pid = blockIdx.x - 64;   // 0..127
        const float inv = 1.0f / 1023.0f;
        #pragma unroll
        for (int e = 0; e < 16; ++e) {
            const int p  = pid * 4096 + e * 256 + t;   // 0 .. 2^19-1
            const int c  = (p & 63) * 2;
            const int r  = (p >> 6) & 127;
            const int h  = (p >> 13) & 7;
            const int isP = (p >> 16) & 1;
            const int l  = (p >> 17) & 3;
            const float* apl = ap + ((size_t)(l * H + h) * 2 + (isP ? 0 : 1)) * DM * DM;
            float v0, v1;
            if (!isP) {
                v0 = (r < DM && c     < DM) ? apl[r * DM + c] * inv     : 0.f;
                v1 = (r < DM && c + 1 < DM) ? apl[r * DM + c + 1] * inv : 0.f;
            } else {
                v0 = (r < DM && c     < DM) ? apl[r * DM + c]     : 0.f;
                v1 = (r < DM && c + 1 < DM) ? apl[r * DM + c + 1]
                     : ((r == DM && c + 1 == DM) ? 1.f : 0.f);
            }
            unsigned short* base = (isP ? Pb : Qb) + (size_t)(l * H + h) * DD;
            const int el = SW(r, c);
            ((unsigned int*)base)[el >> 1] =
                (unsigned int)f2bf(v0) | ((unsigned int)f2bf(v1) << 16);
        }
    }
}

// ---------------------------------------------------------------------------
// gp: Gram partial of chunk c via MFMA from bf16 Ztr; store bf16 in the
// FINAL swizzled G layout (transposed-pack; chunk Gram symmetric — the exact
// r11/r15-proven store). grid (8 chunks, 4 n-quarters, B) = 256 blocks x 256.
// ---------------------------------------------------------------------------
__global__ __launch_bounds__(256) void gp_kernel(
    const unsigned short* __restrict__ Ztr, unsigned short* __restrict__ Gp)
{
    const int c = blockIdx.x, q = blockIdx.y, b = blockIdx.z;
    const int t = threadIdx.x, lane = t & 63, w = t >> 6;

    __shared__ __align__(16) unsigned short Zt[128 * 128]; // 32 KB

    const unsigned short* src = Ztr + (size_t)(b * 8 + c) * DD;
    #pragma unroll
    for (int i = 0; i < 8; ++i)
        async16((const char*)src + (t + 256 * i) * 16, (char*)Zt + (t + 256 * i) * 16);
    __syncthreads();

    f32x4 acc[2][2] = {};
    #pragma unroll
    for (int k0 = 0; k0 < 128; k0 += 32) {
        const bf16x8 a0 = fragAB(Zt, (w * 2 + 0) * 16, k0, lane);
        const bf16x8 a1 = fragAB(Zt, (w * 2 + 1) * 16, k0, lane);
        const bf16x8 b0 = fragAB(Zt, q * 32,      k0, lane);
        const bf16x8 b1 = fragAB(Zt, q * 32 + 16, k0, lane);
        acc[0][0] = MFMA(a0, b0, acc[0][0]);
        acc[0][1] = MFMA(a0, b1, acc[0][1]);
        acc[1][0] = MFMA(a1, b0, acc[1][0]);
        acc[1][1] = MFMA(a1, b1, acc[1][1]);
    }

    // bf16 transposed-pack store in the final swizzled layout (symmetric)
    unsigned short* Gb = Gp + ((size_t)(b * 8 + c)) * DD;
    #pragma unroll
    for (int m = 0; m < 2; ++m) {
        const int rg0 = (w * 2 + m) * 16 + ((lane >> 4) << 2);
        #pragma unroll
        for (int nl = 0; nl < 2; ++nl) {
            const int cg = q * 32 + nl * 16 + (lane & 15);
            *(ushort4v*)&Gb[SW(cg, rg0)] = packbf(acc[m][nl]);
        }
    }
}

// ---------------------------------------------------------------------------
// gred: Gbf = bf16( sum_c Gp[b][c] ) — partials already in final layout, so
// a pure element-wise ushort8 stream-sum (sred-proven body). grid (8, B) x 256.
// ---------------------------------------------------------------------------
__global__ __launch_bounds__(256) void gred_kernel(
    const unsigned short* __restrict__ Gp, unsigned short* __restrict__ Gbf)
{
    const int b = blockIdx.y;
    const int ch = blockIdx.x * 256 + threadIdx.x;   // 0..2047 ushort8 chunks
    const unsigned short* gp0 = Gp + (size_t)b * 8 * DD;
    float a[8] = {0.f, 0.f, 0.f, 0.f, 0.f, 0.f, 0.f, 0.f};
    #pragma unroll
    for (int c = 0; c < 8; ++c) {
        const ushort8 uu = *(const ushort8*)&gp0[(size_t)c * DD + ch * 8];
        #pragma unroll
        for (int e = 0; e < 8; ++e) a[e] += bf2f(uu[e]);
    }
    ushort8 o;
    #pragma unroll
    for (int e = 0; e < 8; ++e) o[e] = f2bf(a[e]);
    *(ushort8*)&Gbf[(size_t)b * DD + ch * 8] = o;
}

// ---------------------------------------------------------------------------
// ts: T = Qf_h @ G_b; Spt = (T @ P_h^T)^T stored bf16 in the FINAL swizzled
// S^T layout (r11/r15-proven). grid (4, H, B) x 256.
// ---------------------------------------------------------------------------
__global__ __launch_bounds__(256) void ts_kernel(
    const unsigned short* __restrict__ Qb, const unsigned short* __restrict__ Pb,
    const unsigned short* __restrict__ Gbf, unsigned short* __restrict__ Spt)
{
    const int s = blockIdx.x, h = blockIdx.y, b = blockIdx.z;
    const int t = threadIdx.x, lane = t & 63, w = t >> 6;

    __shared__ __align__(16) unsigned short Qs[32 * 128];   // 8 KB
    __shared__ __align__(16) unsigned short Gs[128 * 128];  // 32 KB
    __shared__ __align__(16) unsigned short Ps[128 * 128];  // 32 KB
    __shared__ __align__(16) unsigned short Tb[32 * 128];   // 8 KB

    const unsigned short* qsrc = Qb + (size_t)h * DD + s * 32 * 128;
    #pragma unroll
    for (int i = 0; i < 2; ++i)
        async16((const char*)qsrc + (t + 256 * i) * 16, (char*)Qs + (t + 256 * i) * 16);
    const unsigned short* gsrc = Gbf + (size_t)b * DD;
    #pragma unroll
    for (int i = 0; i < 8; ++i)
        async16((const char*)gsrc + (t + 256 * i) * 16, (char*)Gs + (t + 256 * i) * 16);
    const unsigned short* psrc = Pb + (size_t)h * DD;
    #pragma unroll
    for (int i = 0; i < 8; ++i)
        async16((const char*)psrc + (t + 256 * i) * 16, (char*)Ps + (t + 256 * i) * 16);

    // wait for Q+G; Ps's 8 loads stay in flight under phase 1
    asm volatile("s_waitcnt vmcnt(8)" ::: "memory");
    __builtin_amdgcn_s_barrier();
    asm volatile("" ::: "memory");

    f32x4 accT[2][2] = {};
    #pragma unroll
    for (int k0 = 0; k0 < 128; k0 += 32) {
        const bf16x8 a0 = fragAB(Qs, 0, k0, lane);
        const bf16x8 a1 = fragAB(Qs, 16, k0, lane);
        const bf16x8 b0 = fragAB(Gs, (w * 2 + 0) * 16, k0, lane);
        const bf16x8 b1 = fragAB(Gs, (w * 2 + 1) * 16, k0, lane);
        accT[0][0] = MFMA(a0, b0, accT[0][0]);
        accT[0][1] = MFMA(a0, b1, accT[0][1]);
        accT[1][0] = MFMA(a1, b0, accT[1][0]);
        accT[1][1] = MFMA(a1, b1, accT[1][1]);
    }
    #pragma unroll
    for (int m = 0; m < 2; ++m) {
        #pragma unroll
        for (int nl = 0; nl < 2; ++nl) {
            const int cc = (w * 2 + nl) * 16 + (lane & 15);
            const int r0 = m * 16 + ((lane >> 4) << 2);
            #pragma unroll
            for (int j = 0; j < 4; ++j)
                Tb[SW(r0 + j, cc)] = f2bf(accT[m][nl][j]);
        }
    }
    __syncthreads();   // T visible; drains Ps loads

    f32x4 accS[2][2] = {};
    #pragma unroll
    for (int k0 = 0; k0 < 128; k0 += 32) {
        const bf16x8 a0 = fragAB(Tb, 0, k0, lane);
        const bf16x8 a1 = fragAB(Tb, 16, k0, lane);
        const bf16x8 b0 = fragAB(Ps, (w * 2 + 0) * 16, k0, lane);
        const bf16x8 b1 = fragAB(Ps, (w * 2 + 1) * 16, k0, lane);
        accS[0][0] = MFMA(a0, b0, accS[0][0]);
        accS[0][1] = MFMA(a0, b1, accS[0][1]);
        accS[1][0] = MFMA(a1, b0, accS[1][0]);
        accS[1][1] = MFMA(a1, b1, accS[1][1]);
    }

    // bf16 transposed-packed store in the FINAL S^T swizzled layout
    unsigned short* dst = Spt + (size_t)(b * 8 + h) * DD;
    #pragma unroll
    for (int m = 0; m < 2; ++m) {
        const int rg0 = s * 32 + m * 16 + ((lane >> 4) << 2);
        #pragma unroll
        for (int nl = 0; nl < 2; ++nl) {
            const int cg = (w * 2 + nl) * 16 + (lane & 15);
            *(ushort4v*)&dst[SW(cg, rg0)] = packbf(accS[m][nl]);
        }
    }
}

// ---------------------------------------------------------------------------
// sred: St = bf16( sum_h Spt[b][h] ) — element-wise ushort8 stream-sum.
// grid (8, B) x 256. (r15-proven)
// ---------------------------------------------------------------------------
__global__ __launch_bounds__(256) void sred_kernel(
    const unsigned short* __restrict__ Spt, unsigned short* __restrict__ St)
{
    const int b = blockIdx.y;
    const int ch = blockIdx.x * 256 + threadIdx.x;   // 0..2047 ushort8 chunks
    const unsigned short* sp0 = Spt + (size_t)b * 8 * DD;
    float a[8] = {0.f, 0.f, 0.f, 0.f, 0.f, 0.f, 0.f, 0.f};
    #pragma unroll
    for (int h = 0; h < 8; ++h) {
        const ushort8 uu = *(const ushort8*)&sp0[(size_t)h * DD + ch * 8];
        #pragma unroll
        for (int e = 0; e < 8; ++e) a[e] += bf2f(uu[e]);
    }
    ushort8 o;
    #pragma unroll
    for (int e = 0; e < 8; ++e) o[e] = f2bf(a[e]);
    *(ushort8*)&St[(size_t)b * DD + ch * 8] = o;
}

// ---------------------------------------------------------------------------
// z: out = Z + Z @ S via MFMA; also emits next layer's Ztr (bf16 transposed
// swizzled, token-1023-masked) straight from the epilogue registers.
// grid (32, B) x 256. LDS = 56 KB. (r10/r13-proven)
// ---------------------------------------------------------------------------
__global__ __launch_bounds__(256) void z_kernel(
    const float* __restrict__ Zin, const unsigned short* __restrict__ St,
    float* __restrict__ Zout, unsigned short* __restrict__ Ztr, int writeZtr)
{
    const int sblk = blockIdx.x, b = blockIdx.y;
    const int t = threadIdx.x, lane = t & 63, w = t >> 6;

    __shared__ __align__(16) float Zs[32 * 128];            // 16 KB fp32 staging
    __shared__ __align__(16) unsigned short Zb[32 * 128];   // 8 KB bf16 swizzled
    __shared__ __align__(16) unsigned short Ss[128 * 128];  // 32 KB bf16 swizzled (S^T)

    const float* zsrc = Zin + ((size_t)b * NP1 + sblk * 32) * D;
    #pragma unroll
    for (int i = 0; i < 4; ++i)
        async16(zsrc + (t + 256 * i) * 4, Zs + (t + 256 * i) * 4);
    const unsigned short* ssrc = St + (size_t)b * DD;
    #pragma unroll
    for (int i = 0; i < 8; ++i)
        async16((const char*)ssrc + (t + 256 * i) * 16, (char*)Ss + (t + 256 * i) * 16);

    asm volatile("s_waitcnt vmcnt(8)" ::: "memory");
    __builtin_amdgcn_s_barrier();
    asm volatile("" ::: "memory");

    {
        const int r = t >> 3, c0 = (t & 7) * 16;
        const int sft = (r & 7) << 3;
        #pragma unroll
        for (int cc = 0; cc < 16; cc += 2) {
            const float v0 = Zs[r * 128 + c0 + cc];
            const float v1 = Zs[r * 128 + c0 + cc + 1];
            ((unsigned int*)Zb)[(r * 128 + ((c0 + cc) ^ sft)) >> 1] =
                (unsigned int)f2bf(v0) | ((unsigned int)f2bf(v1) << 16);
        }
    }
    __syncthreads();   // Zb visible; drains Ss loads

    f32x4 accR[2][2] = {};
    #pragma unroll
    for (int k0 = 0; k0 < 128; k0 += 32) {
        const bf16x8 a0 = fragAB(Zb, 0, k0, lane);
        const bf16x8 a1 = fragAB(Zb, 16, k0, lane);
        const bf16x8 b0 = fragAB(Ss, (w * 2 + 0) * 16, k0, lane);
        const bf16x8 b1 = fragAB(Ss, (w * 2 + 1) * 16, k0, lane);
        accR[0][0] = MFMA(a0, b0, accR[0][0]);
        accR[0][1] = MFMA(a0, b1, accR[0][1]);
        accR[1][0] = MFMA(a1, b0, accR[1][0]);
        accR[1][1] = MFMA(a1, b1, accR[1][1]);
    }

    // epilogue: out = Zs + res; optional transposed bf16 emit for next gp
    #pragma unroll
    for (int m = 0; m < 2; ++m) {
        const int r0 = m * 16 + ((lane >> 4) << 2);
        #pragma unroll
        for (int nl = 0; nl < 2; ++nl) {
            const int cc = (w * 2 + nl) * 16 + (lane & 15);
            float o[4];
            #pragma unroll
            for (int j = 0; j < 4; ++j) {
                const int r = r0 + j;
                o[j] = Zs[r * 128 + cc] + accR[m][nl][j];
                Zout[((size_t)b * NP1 + sblk * 32 + r) * D + cc] = o[j];
            }
            if (writeZtr) {
                const int gt0   = sblk * 32 + r0;       // global token of j=0
                const int chunk = gt0 >> 7;
                const int tok0  = gt0 & 127;            // 4-aligned -> 8B run contiguous under SW
                ushort4v v;
                #pragma unroll
                for (int j = 0; j < 4; ++j)
                    v[j] = (gt0 + j == 1023) ? (unsigned short)0 : f2bf(o[j]);
                unsigned short* tile = Ztr + (size_t)(b * 8 + chunk) * DD;
                *(ushort4v*)&tile[SW(cc, tok0)] = v;
            }
        }
    }
}

// ---------------------------------------------------------------------------
extern "C" void kernel_launch(void* const* d_in, const int* in_sizes, int n_in,
                              void* d_out, int out_size, void* d_ws, size_t ws_size,
                              hipStream_t stream)
{
    const float* Z0 = (const float*)d_in[0];
    const float* ap = (const float*)d_in[1];
    float* out = (float*)d_out;
    float* ws  = (float*)d_ws;

    unsigned short* Gp  = (unsigned short*)(ws + WS_GP);
    unsigned short* Spt = (unsigned short*)(ws + WS_SPT);
    unsigned short* Qb  = (unsigned short*)(ws + WS_QB);
    unsigned short* Pb  = (unsigned short*)(ws + WS_PB);
    unsigned short* Gbf = (unsigned short*)(ws + WS_GB);
    unsigned short* St  = (unsigned short*)(ws + WS_ST);
    unsigned short* Ztr = (unsigned short*)(ws + WS_ZT);

    hipLaunchKernelGGL(init_kernel, dim3(192), dim3(256), 0, stream, Z0, Ztr, ap, Qb, Pb);

    const float* Zcur = Z0;
    for (int l = 0; l < NL; ++l) {
        const unsigned short* Qbl = Qb + (size_t)l * H * DD;
        const unsigned short* Pbl = Pb + (size_t)l * H * DD;
        hipLaunchKernelGGL(gp_kernel,   dim3(8, 4, B), dim3(256), 0, stream, Ztr, Gp);
        hipLaunchKernelGGL(gred_kernel, dim3(8, B),    dim3(256), 0, stream, Gp, Gbf);
        hipLaunchKernelGGL(ts_kernel,   dim3(4, H, B), dim3(256), 0, stream, Qbl, Pbl, Gbf, Spt);
        hipLaunchKernelGGL(sred_kernel, dim3(8, B),    dim3(256), 0, stream, Spt, St);
        hipLaunchKernelGGL(z_kernel,    dim3(32, B),   dim3(256), 0, stream,
                           Zcur, St, out, Ztr, (l < NL - 1) ? 1 : 0);
        Zcur = out;
    }
}

// Round 17
// 129.228 us; speedup vs baseline: 1.1291x; 1.0231x over previous
//
#include <hip/hip_runtime.h>

// Problem constants
#define D    128      // d+1
#define DM   127      // d
#define NP1  1024     // N+1
#define B    8
#define H    8
#define NL   4
#define DD   (D*D)

typedef __attribute__((ext_vector_type(8))) __bf16 bf16x8;
typedef __attribute__((ext_vector_type(8))) unsigned short ushort8;
typedef __attribute__((ext_vector_type(4))) unsigned short ushort4v;
typedef __attribute__((ext_vector_type(4))) float f32x4;

// Workspace layout (float offsets). ~8.5 MB total.
#define WS_GP  0                        // [B][8][DD] bf16 Gram partials, swizzled (final layout)
#define WS_SPT (WS_GP + B*8*DD/2)       // [B][H][DD] bf16 Sp^T partials, swizzled (final layout)
#define WS_QB  (WS_SPT + B*H*DD/2)      // [NL][H][DD] bf16 Q*(1/N), swizzled
#define WS_PB  (WS_QB + NL*H*DD/2)      // [NL][H][DD] bf16 P padded (+corner 1), swizzled
#define WS_GB  (WS_PB + NL*H*DD/2)      // [B][DD] bf16 G, swizzled
#define WS_ST  (WS_GB + B*DD/2)         // [B][DD] bf16 S^T, swizzled
#define WS_ZT  (WS_ST + B*DD/2)         // [B][8][DD] bf16 Z^T per chunk, swizzled, tok1023-masked

// Async global->LDS, 16B/lane (dest = wave-uniform base + lane*16; linear).
__device__ __forceinline__ void async16(const void* g, void* l)
{
    __builtin_amdgcn_global_load_lds(
        (const __attribute__((address_space(1))) void*)g,
        (__attribute__((address_space(3))) void*)l,
        16, 0, 0);
}

// fp32 -> bf16 round-to-nearest-even
__device__ __forceinline__ unsigned short f2bf(float f)
{
    unsigned int u = __float_as_uint(f);
    u += 0x7fffu + ((u >> 16) & 1u);
    return (unsigned short)(u >> 16);
}
__device__ __forceinline__ float bf2f(unsigned short v)
{
    return __uint_as_float((unsigned int)v << 16);
}

// Swizzled elem index for bf16 [*][128] row-major tiles: col ^= (row&7)<<3.
__device__ __forceinline__ int SW(int row, int col)
{
    return row * 128 + (col ^ ((row & 7) << 3));
}

// A/B fragment from a swizzled bf16 LDS tile: lane supplies matrix row
// row0+(l&15), k = k0 + (l>>4)*8 + j. k-enumeration cancels between A and B.
__device__ __forceinline__ bf16x8 fragAB(const unsigned short* Lb, int row0, int k0, int lane)
{
    const int r = row0 + (lane & 15);
    const int c = (k0 + ((lane >> 4) << 3)) ^ ((r & 7) << 3);
    union { ushort8 u; bf16x8 b; } U;
    U.u = *(const ushort8*)&Lb[r * 128 + c];
    return U.b;
}
__device__ __forceinline__ ushort4v packbf(f32x4 a)
{
    ushort4v v;
    v[0] = f2bf(a[0]); v[1] = f2bf(a[1]); v[2] = f2bf(a[2]); v[3] = f2bf(a[3]);
    return v;
}

#define MFMA(a, b, c) __builtin_amdgcn_mfma_f32_16x16x32_bf16((a), (b), (c), 0, 0, 0)

// ---------------------------------------------------------------------------
// init (once): blocks 0..63 = layer-0 chunk Grams of Z0 computed IN-PLACE
// (r13 stage+transpose body, then r14-proven [2][8] MFMA, r16-proven bf16
// final-layout store — no Ztr round-trip). blocks 64..191 = prep (params ->
// bf16 swz, r9-proven). grid 192 x 256.
// ---------------------------------------------------------------------------
__global__ __launch_bounds__(256) void init_kernel(
    const float* __restrict__ Z, unsigned short* __restrict__ Gp,
    const float* __restrict__ ap, unsigned short* __restrict__ Qb,
    unsigned short* __restrict__ Pb)
{
    const int t = threadIdx.x;
    __shared__ __align__(16) float Zs[128 * 128];          // 64 KB
    __shared__ __align__(16) unsigned short Zt[128 * 128]; // 32 KB

    if (blockIdx.x < 64) {
        const int c = blockIdx.x & 7, b = blockIdx.x >> 3;
        const int lane = t & 63, w = t >> 6;

        const float* src = Z + ((size_t)b * NP1 + c * 128) * D;
        #pragma unroll
        for (int i = 0; i < 16; ++i)
            async16(src + (t + 256 * i) * 4, Zs + (t + 256 * i) * 4);
        __syncthreads();

        {
            const int d = t >> 1, half = t & 1;
            const int sft = (d & 7) << 3;
            #pragma unroll 4
            for (int tp = 0; tp < 32; ++tp) {
                const int tk = ((tp + d) & 31) * 2 + half * 64;
                float v0 = Zs[tk * 128 + d];
                float v1 = Zs[(tk + 1) * 128 + d];
                if (c == 7 && tk == 126) v1 = 0.f;   // key mask: token 1023
                ((unsigned int*)Zt)[(d * 128 + (tk ^ sft)) >> 1] =
                    (unsigned int)f2bf(v0) | ((unsigned int)f2bf(v1) << 16);
            }
        }
        __syncthreads();

        // full 128x128 chunk Gram: wave w = m-tiles {2w,2w+1} x 8 n-tiles
        f32x4 acc[2][8] = {};
        #pragma unroll
        for (int k0 = 0; k0 < 128; k0 += 32) {
            const bf16x8 a0 = fragAB(Zt, (w * 2 + 0) * 16, k0, lane);
            const bf16x8 a1 = fragAB(Zt, (w * 2 + 1) * 16, k0, lane);
            #pragma unroll
            for (int nt = 0; nt < 8; ++nt) {
                const bf16x8 bb = fragAB(Zt, nt * 16, k0, lane);
                acc[0][nt] = MFMA(a0, bb, acc[0][nt]);
                acc[1][nt] = MFMA(a1, bb, acc[1][nt]);
            }
        }
        // bf16 transposed-pack store in the final swizzled layout (symmetric)
        unsigned short* Gb = Gp + ((size_t)(b * 8 + c)) * DD;
        #pragma unroll
        for (int m = 0; m < 2; ++m) {
            const int rg0 = (w * 2 + m) * 16 + ((lane >> 4) << 2);
            #pragma unroll
            for (int nt = 0; nt < 8; ++nt) {
                const int cg = nt * 16 + (lane & 15);
                *(ushort4v*)&Gb[SW(cg, rg0)] = packbf(acc[m][nt]);
            }
        }
    } else {
        const int pid = blockIdx.x - 64;   // 0..127
        const float inv = 1.0f / 1023.0f;
        #pragma unroll
        for (int e = 0; e < 16; ++e) {
            const int p  = pid * 4096 + e * 256 + t;   // 0 .. 2^19-1
            const int c  = (p & 63) * 2;
            const int r  = (p >> 6) & 127;
            const int h  = (p >> 13) & 7;
            const int isP = (p >> 16) & 1;
            const int l  = (p >> 17) & 3;
            const float* apl = ap + ((size_t)(l * H + h) * 2 + (isP ? 0 : 1)) * DM * DM;
            float v0, v1;
            if (!isP) {
                v0 = (r < DM && c     < DM) ? apl[r * DM + c] * inv     : 0.f;
                v1 = (r < DM && c + 1 < DM) ? apl[r * DM + c + 1] * inv : 0.f;
            } else {
                v0 = (r < DM && c     < DM) ? apl[r * DM + c]     : 0.f;
                v1 = (r < DM && c + 1 < DM) ? apl[r * DM + c + 1]
                     : ((r == DM && c + 1 == DM) ? 1.f : 0.f);
            }
            unsigned short* base = (isP ? Pb : Qb) + (size_t)(l * H + h) * DD;
            const int el = SW(r, c);
            ((unsigned int*)base)[el >> 1] =
                (unsigned int)f2bf(v0) | ((unsigned int)f2bf(v1) << 16);
        }
    }
}

// ---------------------------------------------------------------------------
// gp (layers 1..3): Gram partial of chunk c via MFMA from bf16 Ztr; store
// bf16 in the FINAL swizzled G layout. grid (8, 4, B) = 256 x 256. (r16-proven)
// ---------------------------------------------------------------------------
__global__ __launch_bounds__(256) void gp_kernel(
    const unsigned short* __restrict__ Ztr, unsigned short* __restrict__ Gp)
{
    const int c = blockIdx.x, q = blockIdx.y, b = blockIdx.z;
    const int t = threadIdx.x, lane = t & 63, w = t >> 6;

    __shared__ __align__(16) unsigned short Zt[128 * 128]; // 32 KB

    const unsigned short* src = Ztr + (size_t)(b * 8 + c) * DD;
    #pragma unroll
    for (int i = 0; i < 8; ++i)
        async16((const char*)src + (t + 256 * i) * 16, (char*)Zt + (t + 256 * i) * 16);
    __syncthreads();

    f32x4 acc[2][2] = {};
    #pragma unroll
    for (int k0 = 0; k0 < 128; k0 += 32) {
        const bf16x8 a0 = fragAB(Zt, (w * 2 + 0) * 16, k0, lane);
        const bf16x8 a1 = fragAB(Zt, (w * 2 + 1) * 16, k0, lane);
        const bf16x8 b0 = fragAB(Zt, q * 32,      k0, lane);
        const bf16x8 b1 = fragAB(Zt, q * 32 + 16, k0, lane);
        acc[0][0] = MFMA(a0, b0, acc[0][0]);
        acc[0][1] = MFMA(a0, b1, acc[0][1]);
        acc[1][0] = MFMA(a1, b0, acc[1][0]);
        acc[1][1] = MFMA(a1, b1, acc[1][1]);
    }

    unsigned short* Gb = Gp + ((size_t)(b * 8 + c)) * DD;
    #pragma unroll
    for (int m = 0; m < 2; ++m) {
        const int rg0 = (w * 2 + m) * 16 + ((lane >> 4) << 2);
        #pragma unroll
        for (int nl = 0; nl < 2; ++nl) {
            const int cg = q * 32 + nl * 16 + (lane & 15);
            *(ushort4v*)&Gb[SW(cg, rg0)] = packbf(acc[m][nl]);
        }
    }
}

// ---------------------------------------------------------------------------
// gred: Gbf = bf16( sum_c Gp[b][c] ) — element-wise ushort8 stream-sum.
// grid (8, B) x 256. (r16-proven)
// ---------------------------------------------------------------------------
__global__ __launch_bounds__(256) void gred_kernel(
    const unsigned short* __restrict__ Gp, unsigned short* __restrict__ Gbf)
{
    const int b = blockIdx.y;
    const int ch = blockIdx.x * 256 + threadIdx.x;   // 0..2047 ushort8 chunks
    const unsigned short* gp0 = Gp + (size_t)b * 8 * DD;
    float a[8] = {0.f, 0.f, 0.f, 0.f, 0.f, 0.f, 0.f, 0.f};
    #pragma unroll
    for (int c = 0; c < 8; ++c) {
        const ushort8 uu = *(const ushort8*)&gp0[(size_t)c * DD + ch * 8];
        #pragma unroll
        for (int e = 0; e < 8; ++e) a[e] += bf2f(uu[e]);
    }
    ushort8 o;
    #pragma unroll
    for (int e = 0; e < 8; ++e) o[e] = f2bf(a[e]);
    *(ushort8*)&Gbf[(size_t)b * DD + ch * 8] = o;
}

// ---------------------------------------------------------------------------
// ts: T = Qf_h @ G_b; Spt = (T @ P_h^T)^T stored bf16 in the FINAL swizzled
// S^T layout (r11/r15-proven). grid (4, H, B) x 256.
// ---------------------------------------------------------------------------
__global__ __launch_bounds__(256) void ts_kernel(
    const unsigned short* __restrict__ Qb, const unsigned short* __restrict__ Pb,
    const unsigned short* __restrict__ Gbf, unsigned short* __restrict__ Spt)
{
    const int s = blockIdx.x, h = blockIdx.y, b = blockIdx.z;
    const int t = threadIdx.x, lane = t & 63, w = t >> 6;

    __shared__ __align__(16) unsigned short Qs[32 * 128];   // 8 KB
    __shared__ __align__(16) unsigned short Gs[128 * 128];  // 32 KB
    __shared__ __align__(16) unsigned short Ps[128 * 128];  // 32 KB
    __shared__ __align__(16) unsigned short Tb[32 * 128];   // 8 KB

    const unsigned short* qsrc = Qb + (size_t)h * DD + s * 32 * 128;
    #pragma unroll
    for (int i = 0; i < 2; ++i)
        async16((const char*)qsrc + (t + 256 * i) * 16, (char*)Qs + (t + 256 * i) * 16);
    const unsigned short* gsrc = Gbf + (size_t)b * DD;
    #pragma unroll
    for (int i = 0; i < 8; ++i)
        async16((const char*)gsrc + (t + 256 * i) * 16, (char*)Gs + (t + 256 * i) * 16);
    const unsigned short* psrc = Pb + (size_t)h * DD;
    #pragma unroll
    for (int i = 0; i < 8; ++i)
        async16((const char*)psrc + (t + 256 * i) * 16, (char*)Ps + (t + 256 * i) * 16);

    // wait for Q+G; Ps's 8 loads stay in flight under phase 1
    asm volatile("s_waitcnt vmcnt(8)" ::: "memory");
    __builtin_amdgcn_s_barrier();
    asm volatile("" ::: "memory");

    f32x4 accT[2][2] = {};
    #pragma unroll
    for (int k0 = 0; k0 < 128; k0 += 32) {
        const bf16x8 a0 = fragAB(Qs, 0, k0, lane);
        const bf16x8 a1 = fragAB(Qs, 16, k0, lane);
        const bf16x8 b0 = fragAB(Gs, (w * 2 + 0) * 16, k0, lane);
        const bf16x8 b1 = fragAB(Gs, (w * 2 + 1) * 16, k0, lane);
        accT[0][0] = MFMA(a0, b0, accT[0][0]);
        accT[0][1] = MFMA(a0, b1, accT[0][1]);
        accT[1][0] = MFMA(a1, b0, accT[1][0]);
        accT[1][1] = MFMA(a1, b1, accT[1][1]);
    }
    #pragma unroll
    for (int m = 0; m < 2; ++m) {
        #pragma unroll
        for (int nl = 0; nl < 2; ++nl) {
            const int cc = (w * 2 + nl) * 16 + (lane & 15);
            const int r0 = m * 16 + ((lane >> 4) << 2);
            #pragma unroll
            for (int j = 0; j < 4; ++j)
                Tb[SW(r0 + j, cc)] = f2bf(accT[m][nl][j]);
        }
    }
    __syncthreads();   // T visible; drains Ps loads

    f32x4 accS[2][2] = {};
    #pragma unroll
    for (int k0 = 0; k0 < 128; k0 += 32) {
        const bf16x8 a0 = fragAB(Tb, 0, k0, lane);
        const bf16x8 a1 = fragAB(Tb, 16, k0, lane);
        const bf16x8 b0 = fragAB(Ps, (w * 2 + 0) * 16, k0, lane);
        const bf16x8 b1 = fragAB(Ps, (w * 2 + 1) * 16, k0, lane);
        accS[0][0] = MFMA(a0, b0, accS[0][0]);
        accS[0][1] = MFMA(a0, b1, accS[0][1]);
        accS[1][0] = MFMA(a1, b0, accS[1][0]);
        accS[1][1] = MFMA(a1, b1, accS[1][1]);
    }

    // bf16 transposed-packed store in the FINAL S^T swizzled layout
    unsigned short* dst = Spt + (size_t)(b * 8 + h) * DD;
    #pragma unroll
    for (int m = 0; m < 2; ++m) {
        const int rg0 = s * 32 + m * 16 + ((lane >> 4) << 2);
        #pragma unroll
        for (int nl = 0; nl < 2; ++nl) {
            const int cg = (w * 2 + nl) * 16 + (lane & 15);
            *(ushort4v*)&dst[SW(cg, rg0)] = packbf(accS[m][nl]);
        }
    }
}

// ---------------------------------------------------------------------------
// sred: St = bf16( sum_h Spt[b][h] ) — element-wise ushort8 stream-sum.
// grid (8, B) x 256. (r15-proven)
// ---------------------------------------------------------------------------
__global__ __launch_bounds__(256) void sred_kernel(
    const unsigned short* __restrict__ Spt, unsigned short* __restrict__ St)
{
    const int b = blockIdx.y;
    const int ch = blockIdx.x * 256 + threadIdx.x;   // 0..2047 ushort8 chunks
    const unsigned short* sp0 = Spt + (size_t)b * 8 * DD;
    float a[8] = {0.f, 0.f, 0.f, 0.f, 0.f, 0.f, 0.f, 0.f};
    #pragma unroll
    for (int h = 0; h < 8; ++h) {
        const ushort8 uu = *(const ushort8*)&sp0[(size_t)h * DD + ch * 8];
        #pragma unroll
        for (int e = 0; e < 8; ++e) a[e] += bf2f(uu[e]);
    }
    ushort8 o;
    #pragma unroll
    for (int e = 0; e < 8; ++e) o[e] = f2bf(a[e]);
    *(ushort8*)&St[(size_t)b * DD + ch * 8] = o;
}

// ---------------------------------------------------------------------------
// z: out = Z + Z @ S via MFMA; also emits next layer's Ztr (bf16 transposed
// swizzled, token-1023-masked) straight from the epilogue registers.
// grid (32, B) x 256. LDS = 56 KB. (r10/r13-proven)
// ---------------------------------------------------------------------------
__global__ __launch_bounds__(256) void z_kernel(
    const float* __restrict__ Zin, const unsigned short* __restrict__ St,
    float* __restrict__ Zout, unsigned short* __restrict__ Ztr, int writeZtr)
{
    const int sblk = blockIdx.x, b = blockIdx.y;
    const int t = threadIdx.x, lane = t & 63, w = t >> 6;

    __shared__ __align__(16) float Zs[32 * 128];            // 16 KB fp32 staging
    __shared__ __align__(16) unsigned short Zb[32 * 128];   // 8 KB bf16 swizzled
    __shared__ __align__(16) unsigned short Ss[128 * 128];  // 32 KB bf16 swizzled (S^T)

    const float* zsrc = Zin + ((size_t)b * NP1 + sblk * 32) * D;
    #pragma unroll
    for (int i = 0; i < 4; ++i)
        async16(zsrc + (t + 256 * i) * 4, Zs + (t + 256 * i) * 4);
    const unsigned short* ssrc = St + (size_t)b * DD;
    #pragma unroll
    for (int i = 0; i < 8; ++i)
        async16((const char*)ssrc + (t + 256 * i) * 16, (char*)Ss + (t + 256 * i) * 16);

    asm volatile("s_waitcnt vmcnt(8)" ::: "memory");
    __builtin_amdgcn_s_barrier();
    asm volatile("" ::: "memory");

    {
        const int r = t >> 3, c0 = (t & 7) * 16;
        const int sft = (r & 7) << 3;
        #pragma unroll
        for (int cc = 0; cc < 16; cc += 2) {
            const float v0 = Zs[r * 128 + c0 + cc];
            const float v1 = Zs[r * 128 + c0 + cc + 1];
            ((unsigned int*)Zb)[(r * 128 + ((c0 + cc) ^ sft)) >> 1] =
                (unsigned int)f2bf(v0) | ((unsigned int)f2bf(v1) << 16);
        }
    }
    __syncthreads();   // Zb visible; drains Ss loads

    f32x4 accR[2][2] = {};
    #pragma unroll
    for (int k0 = 0; k0 < 128; k0 += 32) {
        const bf16x8 a0 = fragAB(Zb, 0, k0, lane);
        const bf16x8 a1 = fragAB(Zb, 16, k0, lane);
        const bf16x8 b0 = fragAB(Ss, (w * 2 + 0) * 16, k0, lane);
        const bf16x8 b1 = fragAB(Ss, (w * 2 + 1) * 16, k0, lane);
        accR[0][0] = MFMA(a0, b0, accR[0][0]);
        accR[0][1] = MFMA(a0, b1, accR[0][1]);
        accR[1][0] = MFMA(a1, b0, accR[1][0]);
        accR[1][1] = MFMA(a1, b1, accR[1][1]);
    }

    // epilogue: out = Zs + res; optional transposed bf16 emit for next gp
    #pragma unroll
    for (int m = 0; m < 2; ++m) {
        const int r0 = m * 16 + ((lane >> 4) << 2);
        #pragma unroll
        for (int nl = 0; nl < 2; ++nl) {
            const int cc = (w * 2 + nl) * 16 + (lane & 15);
            float o[4];
            #pragma unroll
            for (int j = 0; j < 4; ++j) {
                const int r = r0 + j;
                o[j] = Zs[r * 128 + cc] + accR[m][nl][j];
                Zout[((size_t)b * NP1 + sblk * 32 + r) * D + cc] = o[j];
            }
            if (writeZtr) {
                const int gt0   = sblk * 32 + r0;       // global token of j=0
                const int chunk = gt0 >> 7;
                const int tok0  = gt0 & 127;            // 4-aligned -> 8B run contiguous under SW
                ushort4v v;
                #pragma unroll
                for (int j = 0; j < 4; ++j)
                    v[j] = (gt0 + j == 1023) ? (unsigned short)0 : f2bf(o[j]);
                unsigned short* tile = Ztr + (size_t)(b * 8 + chunk) * DD;
                *(ushort4v*)&tile[SW(cc, tok0)] = v;
            }
        }
    }
}

// ---------------------------------------------------------------------------
extern "C" void kernel_launch(void* const* d_in, const int* in_sizes, int n_in,
                              void* d_out, int out_size, void* d_ws, size_t ws_size,
                              hipStream_t stream)
{
    const float* Z0 = (const float*)d_in[0];
    const float* ap = (const float*)d_in[1];
    float* out = (float*)d_out;
    float* ws  = (float*)d_ws;

    unsigned short* Gp  = (unsigned short*)(ws + WS_GP);
    unsigned short* Spt = (unsigned short*)(ws + WS_SPT);
    unsigned short* Qb  = (unsigned short*)(ws + WS_QB);
    unsigned short* Pb  = (unsigned short*)(ws + WS_PB);
    unsigned short* Gbf = (unsigned short*)(ws + WS_GB);
    unsigned short* St  = (unsigned short*)(ws + WS_ST);
    unsigned short* Ztr = (unsigned short*)(ws + WS_ZT);

    // init computes layer-0 Gram partials directly (no Ztr round-trip)
    hipLaunchKernelGGL(init_kernel, dim3(192), dim3(256), 0, stream, Z0, Gp, ap, Qb, Pb);

    const float* Zcur = Z0;
    for (int l = 0; l < NL; ++l) {
        const unsigned short* Qbl = Qb + (size_t)l * H * DD;
        const unsigned short* Pbl = Pb + (size_t)l * H * DD;
        if (l > 0)
            hipLaunchKernelGGL(gp_kernel, dim3(8, 4, B), dim3(256), 0, stream, Ztr, Gp);
        hipLaunchKernelGGL(gred_kernel, dim3(8, B),    dim3(256), 0, stream, Gp, Gbf);
        hipLaunchKernelGGL(ts_kernel,   dim3(4, H, B), dim3(256), 0, stream, Qbl, Pbl, Gbf, Spt);
        hipLaunchKernelGGL(sred_kernel, dim3(8, B),    dim3(256), 0, stream, Spt, St);
        hipLaunchKernelGGL(z_kernel,    dim3(32, B),   dim3(256), 0, stream,
                           Zcur, St, out, Ztr, (l < NL - 1) ? 1 : 0);
        Zcur = out;
    }
}